// Round 11
// baseline (346.183 us; speedup 1.0000x reference)
//
#include <hip/hip_runtime.h>
#include <hip/hip_bf16.h>
#include <cstdint>
#include <cstddef>

typedef __attribute__((ext_vector_type(4))) float f32x4;
typedef __attribute__((ext_vector_type(8))) short s16x8;
typedef __attribute__((ext_vector_type(4))) unsigned int u32x4;

#define SDIM 4096
#define DDIM 256
#define NCH 8

#define GLOAD_LDS16(g, s)                                                      \
  __builtin_amdgcn_global_load_lds(                                            \
      (const __attribute__((address_space(1))) void*)(g),                      \
      (__attribute__((address_space(3))) void*)(s), 16, 0, 0)

// round-to-nearest-even f32 -> bf16 bits
__device__ __forceinline__ unsigned short cvt_bf16(float f) {
  union { float f; unsigned int u; } v;
  v.f = f;
  unsigned int u = v.u;
  unsigned int r = (u + 0x7FFFu + ((u >> 16) & 1u)) >> 16;
  return (unsigned short)r;
}

__device__ __forceinline__ float bf2f(unsigned short s) {
  union { unsigned int u; float f; } v;
  v.u = ((unsigned int)s) << 16;
  return v.f;
}

// ---------------- W -> bf16 (+ zero merge counters) ----------------
__global__ __launch_bounds__(256) void k_convw(const float* __restrict__ W,
                                               unsigned short* __restrict__ Wb,
                                               int* __restrict__ Cnt) {
  if (blockIdx.x == 0 && threadIdx.x < 128) Cnt[threadIdx.x] = 0;
  int i = (blockIdx.x * 256 + threadIdx.x) * 8;
  f32x4 a = *(const f32x4*)(W + i);
  f32x4 b = *(const f32x4*)(W + i + 4);
  s16x8 o;
#pragma unroll
  for (int j = 0; j < 4; ++j) {
    o[j] = (short)cvt_bf16(a[j]);
    o[4 + j] = (short)cvt_bf16(b[j]);
  }
  *(s16x8*)(Wb + i) = o;
}

// ---------------- fused: Kp = (E @ W^T) * (log2e/16)  AND  Vt = E^T (bf16) ------------
__global__ __launch_bounds__(256) void k_projv(const float* __restrict__ E,
                                               const unsigned short* __restrict__ Wb,
                                               unsigned short* __restrict__ Kp,
                                               unsigned short* __restrict__ Vt) {
  __shared__ unsigned short tile[64][264];  // 33792 B
  const int tid = threadIdx.x;
  const int w = tid >> 6, l = tid & 63, lhi = l >> 4, llo = l & 15;
  const int m0g = blockIdx.x * 64;
  const int m0 = m0g + w * 16;
  f32x4 acc[16];
#pragma unroll
  for (int n = 0; n < 16; ++n) acc[n] = (f32x4){0.f, 0.f, 0.f, 0.f};
  const float* arow = E + (size_t)(m0 + llo) * DDIM;
#pragma unroll
  for (int kd = 0; kd < 8; ++kd) {
    const int dbase = kd * 32 + lhi * 8;
    f32x4 a0 = *(const f32x4*)(arow + dbase);
    f32x4 a1 = *(const f32x4*)(arow + dbase + 4);
    s16x8 af;
#pragma unroll
    for (int j = 0; j < 4; ++j) {
      af[j] = (short)cvt_bf16(a0[j]);
      af[4 + j] = (short)cvt_bf16(a1[j]);
    }
    *(s16x8*)(&tile[w * 16 + llo][dbase]) = af;  // park bf16 row for transpose
#pragma unroll
    for (int n = 0; n < 16; ++n) {
      s16x8 bf = *(const s16x8*)(Wb + (n * 16 + llo) * DDIM + dbase);
      acc[n] = __builtin_amdgcn_mfma_f32_16x16x32_bf16(af, bf, acc[n], 0, 0, 0);
    }
  }
  __syncthreads();
  {  // transpose out: thread tid owns d = tid
    const int d = tid;
    const int b = m0g >> 12, s0 = m0g & 4095;
    unsigned short* vo = Vt + ((size_t)(b * DDIM) + d) * SDIM + s0;
#pragma unroll
    for (int g = 0; g < 8; ++g) {
      s16x8 pk;
#pragma unroll
      for (int j = 0; j < 8; ++j) pk[j] = (short)tile[g * 8 + j][d];
      *(s16x8*)(vo + g * 8) = pk;
    }
  }
  const float sc = 1.4426950408889634f / 16.0f;  // log2e / sqrt(D)
#pragma unroll
  for (int n = 0; n < 16; ++n) {
#pragma unroll
    for (int r = 0; r < 4; ++r) {
      Kp[(size_t)(m0 + lhi * 4 + r) * DDIM + n * 16 + llo] = cvt_bf16(acc[n][r] * sc);
    }
  }
}

// ---------------- flash attention (exact r4 structure) + in-kernel merge ----------------
// 256 thr (4 waves); q-block 128 rows, wave owns 32 (2x16 subtiles); KVBLK=32; nch=8.
// Swapped MFMA: S^T = mfma(K,Q); P via per-wave LDS scratch; O^T = mfma(V^T,P).
// LDS: K0@0 K1@16K (XOR-swizzled rows); V0@32K V1@48K [d 256][oct 4][8 kv]; P@64K.
// Tail: device-scope ticket per (qt,b) — last chunk merges all layers and writes out,
// overlapping merge traffic with still-running attention blocks.
__global__ __launch_bounds__(256, 2) void k_attn(const float* __restrict__ E,
                                                 const unsigned short* __restrict__ Kp,
                                                 const unsigned short* __restrict__ Vt,
                                                 unsigned short* __restrict__ Po,
                                                 float* __restrict__ Lp,
                                                 float* __restrict__ out,
                                                 int* __restrict__ Cnt) {
  __shared__ u32x4 smem4[4736];  // 75776 B
  char* smem = (char*)smem4;
  const int tid = threadIdx.x;
  const int l = tid & 63, w = tid >> 6, lhi = l >> 4, llo = l & 15;
  // decode: qt descending; bid%32 -> (ch,b) so XCD = bid%8 serves one batch/parity
  const int u = blockIdx.x % (4 * NCH);
  const int t_ = blockIdx.x / (4 * NCH);
  const int qt = 31 - t_;
  const int b = u & 3, ch = u >> 2;
  const int q0 = qt * 128;
  const int chb = ch * 4 + b;
  const int ntile = 4 * (qt + 1);  // kv tiles of 32
  if (ntile <= ch) return;         // zero-work chunk (not counted in ticket target)
  const int nst = (ntile - ch + NCH - 1) / NCH;
  const int wq0 = q0 + w * 32;

  // Q fragments (B-operand layout): lane col q = subtile base + llo, k = lhi*8+j
  s16x8 qf[2][8];
#pragma unroll
  for (int s = 0; s < 2; ++s) {
    const float* Eq = E + ((size_t)(b * SDIM) + wq0 + s * 16 + llo) * DDIM;
#pragma unroll
    for (int kd = 0; kd < 8; ++kd) {
      f32x4 a0 = *(const f32x4*)(Eq + kd * 32 + lhi * 8);
      f32x4 a1 = *(const f32x4*)(Eq + kd * 32 + lhi * 8 + 4);
#pragma unroll
      for (int j = 0; j < 4; ++j) {
        qf[s][kd][j] = (short)cvt_bf16(a0[j]);
        qf[s][kd][4 + j] = (short)cvt_bf16(a1[j]);
      }
    }
  }

  f32x4 oT[2][16];
#pragma unroll
  for (int s = 0; s < 2; ++s)
#pragma unroll
    for (int n = 0; n < 16; ++n) oT[s][n] = (f32x4){0.f, 0.f, 0.f, 0.f};
  float lsum[2] = {0.f, 0.f};

  // staging precompute (linear LDS dest; rule #21)
  const int trow = tid >> 5;                                // K row mod 8
  const int kcolb = ((tid & 31) << 4) ^ ((trow & 7) << 4);  // inverse-swizzled source col
  const char* KpB = (const char*)Kp + (size_t)b * SDIM * 512;
  const char* VtB = (const char*)Vt + (size_t)b * DDIM * (SDIM * 2);
  const char* vsb = VtB + (size_t)(tid >> 2) * 8192 + (size_t)((tid & 3) * 8) * 2;

  auto stage = [&](int t) {
    const int kv0 = (ch + NCH * t) * 32;
    char* kdst = smem + ((t & 1) * 16384);
    char* vdst = smem + 32768 + ((t & 1) * 16384);
    const char* ks = KpB + (size_t)(kv0 + trow) * 512 + kcolb;
    const char* vs = vsb + (size_t)kv0 * 2;
#pragma unroll
    for (int i = 0; i < 4; ++i)
      GLOAD_LDS16(ks + (size_t)i * 4096, kdst + i * 4096 + tid * 16);
#pragma unroll
    for (int i = 0; i < 4; ++i)
      GLOAD_LDS16(vs + (size_t)i * (64 * 8192), vdst + i * 4096 + tid * 16);
  };

  stage(0);
  char* sPw = smem + 65536 + w * 2560;  // 32 rows x 80B, per wave

  for (int t = 0; t < nst; ++t) {
    const int kv0 = (ch + NCH * t) * 32;
    const char* kb_ = smem + ((t & 1) * 16384);
    const char* vb_ = smem + 32768 + ((t & 1) * 16384);

    __syncthreads();                 // drains vmcnt(0): tile t ready, prev reads done
    if (t + 1 < nst) stage(t + 1);   // prefetch hides under this step's compute

    // S^T = mfma(K, Q): rows = kv, cols = q
#pragma unroll
    for (int kb = 0; kb < 2; ++kb) {
      f32x4 sa0 = (f32x4){0.f, 0.f, 0.f, 0.f};
      f32x4 sa1 = (f32x4){0.f, 0.f, 0.f, 0.f};
      const char* krow = kb_ + (kb * 16 + llo) * 512;
      __builtin_amdgcn_s_setprio(1);
#pragma unroll
      for (int kd = 0; kd < 8; ++kd) {
        s16x8 kf = *(const s16x8*)(krow + ((kd * 64 + lhi * 16) ^ ((llo & 7) << 4)));
        sa0 = __builtin_amdgcn_mfma_f32_16x16x32_bf16(kf, qf[0][kd], sa0, 0, 0, 0);
        sa1 = __builtin_amdgcn_mfma_f32_16x16x32_bf16(kf, qf[1][kd], sa1, 0, 0, 0);
      }
      __builtin_amdgcn_s_setprio(0);
      const int kvr = kv0 + kb * 16 + lhi * 4;
#pragma unroll
      for (int s = 0; s < 2; ++s) {
        const f32x4 sa = s ? sa1 : sa0;
        const int qi = wq0 + s * 16 + llo;
        float pv[4];
#pragma unroll
        for (int rr = 0; rr < 4; ++rr) {
          float v = exp2f(sa[rr] - 32.0f);  // static max: scores bounded ~|9|
          pv[rr] = (kvr + rr > qi) ? 0.0f : v;
        }
        lsum[s] += (pv[0] + pv[1]) + (pv[2] + pv[3]);
        unsigned int w0 = __builtin_amdgcn_perm(__float_as_uint(pv[1]),
                                                __float_as_uint(pv[0]), 0x07060302u);
        unsigned int w1 = __builtin_amdgcn_perm(__float_as_uint(pv[3]),
                                                __float_as_uint(pv[2]), 0x07060302u);
        *(uint2*)(sPw + (s * 16 + llo) * 80 + kb * 32 + lhi * 8) = make_uint2(w0, w1);
      }
    }

    // O^T += mfma(V^T, P): per-wave P, in-wave lgkmcnt ordering only
    s16x8 pb0 = *(const s16x8*)(sPw + llo * 80 + lhi * 16);
    s16x8 pb1 = *(const s16x8*)(sPw + (16 + llo) * 80 + lhi * 16);
    __builtin_amdgcn_s_setprio(1);
#pragma unroll
    for (int n = 0; n < 16; ++n) {
      s16x8 vf = *(const s16x8*)(vb_ + (n * 16 + llo) * 64 + lhi * 16);
      oT[0][n] = __builtin_amdgcn_mfma_f32_16x16x32_bf16(vf, pb0, oT[0][n], 0, 0, 0);
      oT[1][n] = __builtin_amdgcn_mfma_f32_16x16x32_bf16(vf, pb1, oT[1][n], 0, 0, 0);
    }
    __builtin_amdgcn_s_setprio(0);
  }

  // epilogue: reduce l across lhi groups; store unnormalized O^T (bf16) + l (f32)
#pragma unroll
  for (int s = 0; s < 2; ++s) {
    lsum[s] += __shfl_xor(lsum[s], 16);
    lsum[s] += __shfl_xor(lsum[s], 32);
  }
#pragma unroll
  for (int s = 0; s < 2; ++s) {
    const int q = wq0 + s * 16 + llo;
    unsigned short* PoW = Po + ((size_t)chb * SDIM + q) * DDIM;
#pragma unroll
    for (int n = 0; n < 16; ++n) {
      unsigned int w0 = (unsigned int)cvt_bf16(oT[s][n][0]) |
                        ((unsigned int)cvt_bf16(oT[s][n][1]) << 16);
      unsigned int w1 = (unsigned int)cvt_bf16(oT[s][n][2]) |
                        ((unsigned int)cvt_bf16(oT[s][n][3]) << 16);
      *(uint2*)(PoW + n * 16 + lhi * 4) = make_uint2(w0, w1);
    }
    if (lhi == 0) Lp[(size_t)chb * SDIM + q] = lsum[s];
  }

  // ---- in-kernel merge: last-arriving chunk for (qt,b) merges all layers ----
  const int target = (ntile < NCH) ? ntile : NCH;  // chunks with work
  __threadfence();   // publish Po/Lp device-wide (cross-XCD via L2 writeback)
  __syncthreads();   // all waves' stores+fences done
  int* flag = (int*)smem;
  if (tid == 0) {
    int old = atomicAdd(&Cnt[qt * 4 + b], 1);
    *flag = (old == target - 1) ? 1 : 0;
  }
  __syncthreads();
  if (*flag == 0) return;
  __threadfence();   // acquire side: see all other chunks' stores

  float* sInv = (float*)smem;  // 128 per-row 1/l
  if (tid < 128) {
    float lt = 0.f;
    for (int c = 0; c < target; ++c)
      lt += Lp[(size_t)(c * 4 + b) * SDIM + q0 + tid];
    sInv[tid] = 1.0f / lt;
  }
  __syncthreads();
  float* outB = out + ((size_t)(b * SDIM) + q0) * DDIM;
#pragma unroll
  for (int g = 0; g < 16; ++g) {
    const int idx = g * 2048 + tid * 8;
    const int row = idx >> 8;
    float acc[8] = {0.f, 0.f, 0.f, 0.f, 0.f, 0.f, 0.f, 0.f};
    for (int c = 0; c < target; ++c) {
      s16x8 a = *(const s16x8*)(Po + ((size_t)(c * 4 + b) * SDIM + q0) * DDIM + idx);
#pragma unroll
      for (int j = 0; j < 8; ++j) acc[j] += bf2f((unsigned short)a[j]);
    }
    const float inv = sInv[row];
    f32x4 o0, o1;
#pragma unroll
    for (int j = 0; j < 4; ++j) {
      o0[j] = acc[j] * inv;
      o1[j] = acc[4 + j] * inv;
    }
    *(f32x4*)(outB + idx) = o0;
    *(f32x4*)(outB + idx + 4) = o1;
  }
}

extern "C" void kernel_launch(void* const* d_in, const int* in_sizes, int n_in,
                              void* d_out, int out_size, void* d_ws, size_t ws_size,
                              hipStream_t stream) {
  (void)in_sizes; (void)n_in; (void)out_size; (void)ws_size;
  const float* E = (const float*)d_in[0];
  const float* W = (const float*)d_in[1];
  float* out = (float*)d_out;
  char* ws = (char*)d_ws;

  unsigned short* Kp = (unsigned short*)(ws);                // 8 MB bf16 (B*S, D), scaled
  unsigned short* Vt = (unsigned short*)(ws + 8388608);      // 8 MB bf16 per-batch [D][S]
  unsigned short* Po = (unsigned short*)(ws + 16777216);     // 64 MB bf16 partials [32][S][D]
  float* Lp = (float*)(ws + 83886080);                       // 512 KB f32 [32][S]
  unsigned short* Wb = (unsigned short*)(ws + 84410368);     // 128 KB bf16 W
  int* Cnt = (int*)(ws + 84541440);                          // 512 B tickets [32 qt][4 b]

  k_convw<<<dim3(32), dim3(256), 0, stream>>>(W, Wb, Cnt);
  k_projv<<<dim3(256), dim3(256), 0, stream>>>(E, Wb, Kp, Vt);
  k_attn<<<dim3(32 * 4 * NCH), dim3(256), 0, stream>>>(E, Kp, Vt, Po, Lp, out, Cnt);
}

// Round 12
// 130.390 us; speedup vs baseline: 2.6550x; 2.6550x over previous
//
#include <hip/hip_runtime.h>
#include <hip/hip_bf16.h>
#include <cstdint>
#include <cstddef>

typedef __attribute__((ext_vector_type(4))) float f32x4;
typedef __attribute__((ext_vector_type(8))) short s16x8;
typedef __attribute__((ext_vector_type(4))) unsigned int u32x4;

#define SDIM 4096
#define DDIM 256
#define NCH 8

#define GLOAD_LDS16(g, s)                                                      \
  __builtin_amdgcn_global_load_lds(                                            \
      (const __attribute__((address_space(1))) void*)(g),                      \
      (__attribute__((address_space(3))) void*)(s), 16, 0, 0)

// round-to-nearest-even f32 -> bf16 bits
__device__ __forceinline__ unsigned short cvt_bf16(float f) {
  union { float f; unsigned int u; } v;
  v.f = f;
  unsigned int u = v.u;
  unsigned int r = (u + 0x7FFFu + ((u >> 16) & 1u)) >> 16;
  return (unsigned short)r;
}

__device__ __forceinline__ float bf2f(unsigned short s) {
  union { unsigned int u; float f; } v;
  v.u = ((unsigned int)s) << 16;
  return v.f;
}

// ---------------- W -> bf16 ----------------
__global__ __launch_bounds__(256) void k_convw(const float* __restrict__ W,
                                               unsigned short* __restrict__ Wb) {
  int i = (blockIdx.x * 256 + threadIdx.x) * 8;
  f32x4 a = *(const f32x4*)(W + i);
  f32x4 b = *(const f32x4*)(W + i + 4);
  s16x8 o;
#pragma unroll
  for (int j = 0; j < 4; ++j) {
    o[j] = (short)cvt_bf16(a[j]);
    o[4 + j] = (short)cvt_bf16(b[j]);
  }
  *(s16x8*)(Wb + i) = o;
}

// ---------------- fused: Kp = (E @ W^T) * (log2e/16)  AND  Vt = E^T (bf16) ------------
__global__ __launch_bounds__(256) void k_projv(const float* __restrict__ E,
                                               const unsigned short* __restrict__ Wb,
                                               unsigned short* __restrict__ Kp,
                                               unsigned short* __restrict__ Vt) {
  __shared__ unsigned short tile[64][264];  // 33792 B
  const int tid = threadIdx.x;
  const int w = tid >> 6, l = tid & 63, lhi = l >> 4, llo = l & 15;
  const int m0g = blockIdx.x * 64;
  const int m0 = m0g + w * 16;
  f32x4 acc[16];
#pragma unroll
  for (int n = 0; n < 16; ++n) acc[n] = (f32x4){0.f, 0.f, 0.f, 0.f};
  const float* arow = E + (size_t)(m0 + llo) * DDIM;
#pragma unroll
  for (int kd = 0; kd < 8; ++kd) {
    const int dbase = kd * 32 + lhi * 8;
    f32x4 a0 = *(const f32x4*)(arow + dbase);
    f32x4 a1 = *(const f32x4*)(arow + dbase + 4);
    s16x8 af;
#pragma unroll
    for (int j = 0; j < 4; ++j) {
      af[j] = (short)cvt_bf16(a0[j]);
      af[4 + j] = (short)cvt_bf16(a1[j]);
    }
    *(s16x8*)(&tile[w * 16 + llo][dbase]) = af;  // park bf16 row for transpose
#pragma unroll
    for (int n = 0; n < 16; ++n) {
      s16x8 bf = *(const s16x8*)(Wb + (n * 16 + llo) * DDIM + dbase);
      acc[n] = __builtin_amdgcn_mfma_f32_16x16x32_bf16(af, bf, acc[n], 0, 0, 0);
    }
  }
  __syncthreads();
  {  // transpose out: thread tid owns d = tid
    const int d = tid;
    const int b = m0g >> 12, s0 = m0g & 4095;
    unsigned short* vo = Vt + ((size_t)(b * DDIM) + d) * SDIM + s0;
#pragma unroll
    for (int g = 0; g < 8; ++g) {
      s16x8 pk;
#pragma unroll
      for (int j = 0; j < 8; ++j) pk[j] = (short)tile[g * 8 + j][d];
      *(s16x8*)(vo + g * 8) = pk;
    }
  }
  const float sc = 1.4426950408889634f / 16.0f;  // log2e / sqrt(D)
#pragma unroll
  for (int n = 0; n < 16; ++n) {
#pragma unroll
    for (int r = 0; r < 4; ++r) {
      Kp[(size_t)(m0 + lhi * 4 + r) * DDIM + n * 16 + llo] = cvt_bf16(acc[n][r] * sc);
    }
  }
}

// ---------------- flash attention: r4 per-wave structure, 8-wave blocks ----------------
// 512 thr (8 waves); q-block 256 rows, wave owns 32 (2x16 subtiles); KVBLK=32; nch=8.
// Each 32KB stage event now feeds 8 waves (2x r4) -> prefetch distance doubles in time,
// K/V refetch traffic halves. Chunk ch of q-tile qt has EXACTLY qt+1 steps; block pairs
// (p, 15-p) -> all 256 blocks identical (17 steps). 1 block/CU, 2 waves/SIMD.
// LDS 84KB: K0@0 K1@16K | V0@32K V1@48K [d 256][64B kv] | P@64K (8 waves x 2560B).
// Swapped MFMA: S^T = mfma(K,Q); P via per-wave LDS scratch; O^T = mfma(V^T,P).
__global__ __launch_bounds__(512, 1) void k_attn(const float* __restrict__ E,
                                                 const unsigned short* __restrict__ Kp,
                                                 const unsigned short* __restrict__ Vt,
                                                 unsigned short* __restrict__ Po,
                                                 float* __restrict__ Lp) {
  __shared__ u32x4 smem4[5376];  // 86016 B
  char* smem = (char*)smem4;
  const int tid = threadIdx.x;
  const int l = tid & 63, w = tid >> 6, lhi = l >> 4, llo = l & 15;
  // decode: bid%32 -> (ch,b) so XCD = bid%8 serves one batch/parity; bid>>5 = pair p
  const int u = blockIdx.x & 31;
  const int p = blockIdx.x >> 5;  // 0..7
  const int b = u & 3, ch = u >> 2;
  const int chb = ch * 4 + b;

  // staging constants (linear LDS dest, inverse-swizzled K source; rule #21)
  const int trow = tid >> 5;                                // K row mod 16
  const int kcolb = ((tid & 31) << 4) ^ ((trow & 7) << 4);  // source col bytes
  const char* KpB = (const char*)Kp + (size_t)b * SDIM * 512;
  const char* VtB = (const char*)Vt + (size_t)b * DDIM * (SDIM * 2);
  const char* vsb = VtB + (size_t)(tid >> 2) * 8192 + ((tid & 3) << 4);
  char* sPw = smem + 65536 + w * 2560;  // 32 rows x 80B, per wave

  for (int c2 = 0; c2 < 2; ++c2) {
    const int qt = c2 ? (15 - p) : p;
    const int q0 = qt * 256;
    const int nst = qt + 1;  // exact for every chunk (ntile = 8(qt+1), 8 chunks)
    const int wq0 = q0 + w * 32;

    if (c2) __syncthreads();  // ctx0's last reads done before restage

    // Q fragments (B-operand): lane col q = wq0 + s*16 + llo, k = lhi*8+j
    s16x8 qf[2][8];
#pragma unroll
    for (int s = 0; s < 2; ++s) {
      const float* Eq = E + ((size_t)(b * SDIM) + wq0 + s * 16 + llo) * DDIM;
#pragma unroll
      for (int kd = 0; kd < 8; ++kd) {
        f32x4 a0 = *(const f32x4*)(Eq + kd * 32 + lhi * 8);
        f32x4 a1 = *(const f32x4*)(Eq + kd * 32 + lhi * 8 + 4);
#pragma unroll
        for (int j = 0; j < 4; ++j) {
          qf[s][kd][j] = (short)cvt_bf16(a0[j]);
          qf[s][kd][4 + j] = (short)cvt_bf16(a1[j]);
        }
      }
    }

    f32x4 oT[2][16];
#pragma unroll
    for (int s = 0; s < 2; ++s)
#pragma unroll
      for (int n = 0; n < 16; ++n) oT[s][n] = (f32x4){0.f, 0.f, 0.f, 0.f};
    float lsum[2] = {0.f, 0.f};

    auto stage = [&](int t) {
      const int kv0 = (ch + NCH * t) * 32;
      char* kdst = smem + ((t & 1) * 16384);
      char* vdst = smem + 32768 + ((t & 1) * 16384);
      const char* ks = KpB + (size_t)(kv0 + trow) * 512 + kcolb;
      GLOAD_LDS16(ks, kdst + tid * 16);
      GLOAD_LDS16(ks + 16 * 512, kdst + 8192 + tid * 16);
      const char* vs = vsb + (size_t)kv0 * 2;
      GLOAD_LDS16(vs, vdst + tid * 16);
      GLOAD_LDS16(vs + (size_t)128 * 8192, vdst + 8192 + tid * 16);
    };

    stage(0);

    for (int t = 0; t < nst; ++t) {
      const int kv0 = (ch + NCH * t) * 32;
      const char* kb_ = smem + ((t & 1) * 16384);
      const char* vb_ = smem + 32768 + ((t & 1) * 16384);

      __syncthreads();                 // drains vmcnt(0): tile t ready, prev reads done
      if (t + 1 < nst) stage(t + 1);   // prefetch hides under this step's compute

      // S^T = mfma(K, Q): rows = kv, cols = q
#pragma unroll
      for (int kb = 0; kb < 2; ++kb) {
        f32x4 sa0 = (f32x4){0.f, 0.f, 0.f, 0.f};
        f32x4 sa1 = (f32x4){0.f, 0.f, 0.f, 0.f};
        const char* krow = kb_ + (kb * 16 + llo) * 512;
        __builtin_amdgcn_s_setprio(1);
#pragma unroll
        for (int kd = 0; kd < 8; ++kd) {
          s16x8 kf = *(const s16x8*)(krow + ((kd * 64 + lhi * 16) ^ ((llo & 7) << 4)));
          sa0 = __builtin_amdgcn_mfma_f32_16x16x32_bf16(kf, qf[0][kd], sa0, 0, 0, 0);
          sa1 = __builtin_amdgcn_mfma_f32_16x16x32_bf16(kf, qf[1][kd], sa1, 0, 0, 0);
        }
        __builtin_amdgcn_s_setprio(0);
        const int kvr = kv0 + kb * 16 + lhi * 4;
#pragma unroll
        for (int s = 0; s < 2; ++s) {
          const f32x4 sa = s ? sa1 : sa0;
          const int qi = wq0 + s * 16 + llo;
          float pv[4];
#pragma unroll
          for (int rr = 0; rr < 4; ++rr) {
            float v = exp2f(sa[rr] - 32.0f);  // static max: scores bounded ~|9|
            pv[rr] = (kvr + rr > qi) ? 0.0f : v;
          }
          lsum[s] += (pv[0] + pv[1]) + (pv[2] + pv[3]);
          unsigned int w0 = __builtin_amdgcn_perm(__float_as_uint(pv[1]),
                                                  __float_as_uint(pv[0]), 0x07060302u);
          unsigned int w1 = __builtin_amdgcn_perm(__float_as_uint(pv[3]),
                                                  __float_as_uint(pv[2]), 0x07060302u);
          *(uint2*)(sPw + (s * 16 + llo) * 80 + kb * 32 + lhi * 8) = make_uint2(w0, w1);
        }
      }

      // O^T += mfma(V^T, P): per-wave P, in-wave lgkmcnt ordering only
      s16x8 pb0 = *(const s16x8*)(sPw + llo * 80 + lhi * 16);
      s16x8 pb1 = *(const s16x8*)(sPw + (16 + llo) * 80 + lhi * 16);
      __builtin_amdgcn_s_setprio(1);
#pragma unroll
      for (int n = 0; n < 16; ++n) {
        s16x8 vf = *(const s16x8*)(vb_ + (n * 16 + llo) * 64 + lhi * 16);
        oT[0][n] = __builtin_amdgcn_mfma_f32_16x16x32_bf16(vf, pb0, oT[0][n], 0, 0, 0);
        oT[1][n] = __builtin_amdgcn_mfma_f32_16x16x32_bf16(vf, pb1, oT[1][n], 0, 0, 0);
      }
      __builtin_amdgcn_s_setprio(0);
    }

    // epilogue: reduce l across lhi groups; store unnormalized O^T (bf16) + l (f32)
#pragma unroll
    for (int s = 0; s < 2; ++s) {
      lsum[s] += __shfl_xor(lsum[s], 16);
      lsum[s] += __shfl_xor(lsum[s], 32);
    }
#pragma unroll
    for (int s = 0; s < 2; ++s) {
      const int q = wq0 + s * 16 + llo;
      unsigned short* PoW = Po + ((size_t)chb * SDIM + q) * DDIM;
#pragma unroll
      for (int n = 0; n < 16; ++n) {
        unsigned int w0 = (unsigned int)cvt_bf16(oT[s][n][0]) |
                          ((unsigned int)cvt_bf16(oT[s][n][1]) << 16);
        unsigned int w1 = (unsigned int)cvt_bf16(oT[s][n][2]) |
                          ((unsigned int)cvt_bf16(oT[s][n][3]) << 16);
        *(uint2*)(PoW + n * 16 + lhi * 4) = make_uint2(w0, w1);
      }
      if (lhi == 0) Lp[(size_t)chb * SDIM + q] = lsum[s];
    }
  }
}

// ---------------- merge: out = sum_c(o_c) / sum_c(l_c), cnt = 8 always ----------------
__global__ __launch_bounds__(256) void k_merge(const unsigned short* __restrict__ Po,
                                               const float* __restrict__ Lp,
                                               float* __restrict__ out) {
  const size_t e = ((size_t)blockIdx.x * 256 + threadIdx.x) * 8;
  const size_t f = e >> 8;
  float lt = 0.f;
#pragma unroll
  for (int c = 0; c < NCH; ++c) lt += Lp[(size_t)c * 16384 + f];
  const float inv = 1.0f / lt;
  float acc[8] = {0.f, 0.f, 0.f, 0.f, 0.f, 0.f, 0.f, 0.f};
#pragma unroll
  for (int c = 0; c < NCH; ++c) {
    s16x8 a = *(const s16x8*)(Po + (size_t)c * 4194304 + e);
#pragma unroll
    for (int j = 0; j < 8; ++j) acc[j] += bf2f((unsigned short)a[j]);
  }
  f32x4 o0, o1;
#pragma unroll
  for (int j = 0; j < 4; ++j) {
    o0[j] = acc[j] * inv;
    o1[j] = acc[4 + j] * inv;
  }
  *(f32x4*)(out + e) = o0;
  *(f32x4*)(out + e + 4) = o1;
}

extern "C" void kernel_launch(void* const* d_in, const int* in_sizes, int n_in,
                              void* d_out, int out_size, void* d_ws, size_t ws_size,
                              hipStream_t stream) {
  (void)in_sizes; (void)n_in; (void)out_size; (void)ws_size;
  const float* E = (const float*)d_in[0];
  const float* W = (const float*)d_in[1];
  float* out = (float*)d_out;
  char* ws = (char*)d_ws;

  unsigned short* Kp = (unsigned short*)(ws);                // 8 MB bf16 (B*S, D), scaled
  unsigned short* Vt = (unsigned short*)(ws + 8388608);      // 8 MB bf16 per-batch [D][S]
  unsigned short* Po = (unsigned short*)(ws + 16777216);     // 64 MB bf16 partials [32][S][D]
  float* Lp = (float*)(ws + 83886080);                       // 512 KB f32 [32][S]
  unsigned short* Wb = (unsigned short*)(ws + 84410368);     // 128 KB bf16 W

  k_convw<<<dim3(32), dim3(256), 0, stream>>>(W, Wb);
  k_projv<<<dim3(256), dim3(256), 0, stream>>>(E, Wb, Kp, Vt);
  k_attn<<<dim3(256), dim3(512), 0, stream>>>(E, Kp, Vt, Po, Lp);
  k_merge<<<dim3(2048), dim3(256), 0, stream>>>(Po, Lp, out);
}